// Round 15
// baseline (1909.026 us; speedup 1.0000x reference)
//
#include <hip/hip_runtime.h>
#include <hip/hip_bf16.h>

#define NN 100000
#define EE 1600000
#define HH 128
#define LL 4
#define BN_EPS 1e-5f
#define NPART 6252       // 1563 blocks * 4 waves (k_gru geometry)
#define SCAN_BLK 391     // ceil(100000/256)

typedef __attribute__((ext_vector_type(8))) short bf16x8;
typedef __attribute__((ext_vector_type(4))) float f32x4;
typedef unsigned short u16;

static __device__ __forceinline__ u16 f2bf(float f) {
  unsigned u = __float_as_uint(f);
  u += 0x7FFF + ((u >> 16) & 1);   // RNE
  return (u16)(u >> 16);
}
static __device__ __forceinline__ float bf2f(u16 h) {
  return __uint_as_float(((unsigned)h) << 16);
}
static __device__ __forceinline__ void split8v(const float* v, bf16x8& hi, bf16x8& lo) {
  #pragma unroll
  for (int i = 0; i < 8; ++i) {
    u16 h = f2bf(v[i]);
    hi[i] = (short)h;
    lo[i] = (short)f2bf(v[i] - bf2f(h));
  }
}
// split 8 consecutive f32 (from memory) into hi/lo bf16x8 fragments
static __device__ __forceinline__ void split8(const float* p, bf16x8& hi, bf16x8& lo) {
  float4 a = *(const float4*)p, b = *(const float4*)(p + 4);
  float v[8] = {a.x, a.y, a.z, a.w, b.x, b.y, b.z, b.w};
  split8v(v, hi, lo);
}

// ---------- async global->LDS, 16B per lane (CK-style addrspace casts) ----------
static __device__ __forceinline__ void gload16(const void* g, void* l) {
  __attribute__((address_space(3))) unsigned* lp =
      (__attribute__((address_space(3))) unsigned*)(reinterpret_cast<uintptr_t>(l));
  const __attribute__((address_space(1))) unsigned* gp =
      (const __attribute__((address_space(1))) unsigned*)(reinterpret_cast<uintptr_t>(g));
  __builtin_amdgcn_global_load_lds(gp, lp, 16, 0, 0);
}

// ---------- split f32 -> (hi, lo) bf16 pair (row-major; W1 only) ----------
__global__ void k_split(const float* __restrict__ src, u16* __restrict__ hi,
                        u16* __restrict__ lo, int n4) {
  int i = blockIdx.x * 256 + threadIdx.x;
  if (i >= n4) return;
  float4 v = ((const float4*)src)[i];
  ushort4 h_, l_;
  h_.x = f2bf(v.x); l_.x = f2bf(v.x - bf2f(h_.x));
  h_.y = f2bf(v.y); l_.y = f2bf(v.y - bf2f(h_.y));
  h_.z = f2bf(v.z); l_.z = f2bf(v.z - bf2f(h_.z));
  h_.w = f2bf(v.w); l_.w = f2bf(v.w - bf2f(h_.w));
  ((ushort4*)hi)[i] = h_;
  ((ushort4*)lo)[i] = l_;
}

// ---------- pack GRU weights into nt-major MFMA-linear granule layout ----------
// pW[l][nt][tile=g*4+a][gr=kk*64+lane] (16B granules). Content: array a
// (0=Wf hi,1=Wf lo,2=Whh hi,3=Whh lo), gate g, row g*128+nt*16+(lane&15),
// kcol kk*32+(lane>>4)*8. Wave reads/stages 64 consecutive granules.
__global__ void k_packsplit2(const float* __restrict__ Wff, const float* __restrict__ Whh,
                             u16* __restrict__ pW) {
  int gid = blockIdx.x * 256 + threadIdx.x;   // 4*8*12*256 = 98304
  if (gid >= 98304) return;
  int gr = gid & 255;
  int lane = gr & 63, kk = gr >> 6;
  int rest = gid >> 8;          // 0..383
  int tile = rest % 12;
  int nt = (rest / 12) & 7;
  int l = rest / 96;
  int g = tile >> 2, a = tile & 3;
  int row = g * 128 + nt * 16 + (lane & 15);
  int kcol = kk * 32 + (lane >> 4) * 8;
  const float* src = ((a < 2) ? Wff : Whh) + ((size_t)l * 384 + row) * 128 + kcol;
  bf16x8 h8, l8;
  split8(src, h8, l8);
  *(bf16x8*)(pW + (size_t)gid * 8) = (a & 1) ? l8 : h8;
}

// ---------- edge index dtype probe ----------
__global__ void k_idx_probe(const int* __restrict__ e32, int* __restrict__ flag) {
  if (threadIdx.x == 0 && blockIdx.x == 0) {
    int z = e32[1] | e32[3] | e32[5] | e32[7] | e32[9] | e32[11];
    flag[0] = (z == 0) ? 1 : 0;   // 1 => int64 payload
  }
}

// ---------- CSR build (reads raw edge buffer, no extracted copy) ----------
__global__ void k_hist(const int* __restrict__ e32, const int* __restrict__ flag,
                       int* __restrict__ degi) {
  int i = blockIdx.x * 256 + threadIdx.x;
  if (i < EE) {
    int d = flag[0] ? e32[2 * (size_t)(EE + i)] : e32[EE + i];
    atomicAdd(&degi[d], 1);
  }
}
__global__ void k_scan1(const int* __restrict__ degi, int* __restrict__ curs,
                        int* __restrict__ bsum) {
  __shared__ int s[256];
  int t = threadIdx.x;
  int i = blockIdx.x * 256 + t;
  int v = (i < NN) ? degi[i] : 0;
  s[t] = v;
  __syncthreads();
  #pragma unroll
  for (int o = 1; o < 256; o <<= 1) {
    int u = (t >= o) ? s[t - o] : 0;
    __syncthreads();
    s[t] += u;
    __syncthreads();
  }
  if (i < NN) curs[i] = s[t] - v;     // exclusive
  if (t == 255) bsum[blockIdx.x] = s[255];
}
__global__ void k_scan2(int* __restrict__ bsum) {
  if (threadIdx.x == 0 && blockIdx.x == 0) {
    int run = 0;
    for (int b = 0; b < SCAN_BLK; ++b) { int v = bsum[b]; bsum[b] = run; run += v; }
  }
}
__global__ void k_scan3(int* __restrict__ curs, const int* __restrict__ bsum) {
  int i = blockIdx.x * 256 + threadIdx.x;
  if (i < NN) curs[i] += bsum[blockIdx.x];
}
__global__ void k_scatter(const int* __restrict__ e32, const int* __restrict__ flag,
                          int* __restrict__ curs, int* __restrict__ es) {
  int i = blockIdx.x * 256 + threadIdx.x;
  if (i < EE) {
    int f = flag[0];
    int s = f ? e32[2 * (size_t)i] : e32[i];
    int d = f ? e32[2 * (size_t)(EE + i)] : e32[EE + i];
    int p = atomicAdd(&curs[d], 1);
    es[p] = s;
  }
  // after this kernel: curs[n] == row end of node n (exclusive)
}

// ---------- Wf = Wih @ W2 (f32) ----------
__global__ void k_fuse_wf(const float* __restrict__ Wih, const float* __restrict__ W2,
                          float* __restrict__ Wff) {
  int li = blockIdx.x;             // 0..4*384-1
  int l = li / 384;
  int j = threadIdx.x;             // 0..127
  const float* wr = Wih + (size_t)li * 128;
  const float* w2 = W2 + (size_t)l * 128 * 128;
  float s = 0.f;
  #pragma unroll 8
  for (int k = 0; k < 128; ++k) s += wr[k] * w2[k * 128 + j];
  Wff[(size_t)li * 128 + j] = s;
}

// ---------- c2 = Wih @ b2 ----------
__global__ void k_c2(const float* __restrict__ Wih, const float* __restrict__ b2,
                     float* __restrict__ c2) {
  int gid = blockIdx.x * 256 + threadIdx.x;
  if (gid >= 4 * 384) return;
  int l = gid / 384;
  const float* wr = Wih + (size_t)gid * 128;
  const float* br = b2 + (size_t)l * 128;
  float s = 0.f;
  #pragma unroll 8
  for (int k = 0; k < 128; ++k) s += wr[k] * br[k];
  c2[gid] = s;
}

// ---------- input projection via MFMA (bf16x3): h = relu(x @ Win^T + bin) ----------
__global__ __launch_bounds__(256) void k_inproj2(
    const float* __restrict__ x, const float* __restrict__ Win,
    const float* __restrict__ bin, float* __restrict__ hf) {
  __shared__ u16 xh[64][72], xl[64][72];
  const int t = threadIdx.x;
  const int wv = t >> 6, ln = t & 63;
  const int lr = ln & 15, lg = ln >> 4;
  const int nb = blockIdx.x * 64;

  #pragma unroll
  for (int it = 0; it < 4; ++it) {
    int idx = t + it * 256;            // 0..1023 : 64 rows x 16 float4
    int row = idx >> 4, c4 = idx & 15;
    int node = nb + row;
    float4 v = (node < NN) ? ((const float4*)(x + (size_t)node * 64))[c4]
                           : make_float4(0.f, 0.f, 0.f, 0.f);
    ushort4 h_, l_;
    h_.x = f2bf(v.x); l_.x = f2bf(v.x - bf2f(h_.x));
    h_.y = f2bf(v.y); l_.y = f2bf(v.y - bf2f(h_.y));
    h_.z = f2bf(v.z); l_.z = f2bf(v.z - bf2f(h_.z));
    h_.w = f2bf(v.w); l_.w = f2bf(v.w - bf2f(h_.w));
    *(ushort4*)&xh[row][c4 * 4] = h_;
    *(ushort4*)&xl[row][c4 * 4] = l_;
  }
  __syncthreads();

  f32x4 acc[4][2];
  #pragma unroll
  for (int rt = 0; rt < 4; ++rt)
    #pragma unroll
    for (int nt = 0; nt < 2; ++nt)
      acc[rt][nt] = (f32x4){0.f, 0.f, 0.f, 0.f};

  bf16x8 bh[2][2], bl[2][2];
  #pragma unroll
  for (int nt = 0; nt < 2; ++nt) {
    int c = wv * 32 + nt * 16 + lr;
    #pragma unroll
    for (int kk = 0; kk < 2; ++kk)
      split8(Win + (size_t)c * 64 + kk * 32 + lg * 8, bh[nt][kk], bl[nt][kk]);
  }

  #pragma unroll
  for (int rt = 0; rt < 4; ++rt) {
    bf16x8 ah[2], al[2];
    #pragma unroll
    for (int kk = 0; kk < 2; ++kk) {
      ah[kk] = *(const bf16x8*)(&xh[rt * 16 + lr][kk * 32 + lg * 8]);
      al[kk] = *(const bf16x8*)(&xl[rt * 16 + lr][kk * 32 + lg * 8]);
    }
    #pragma unroll
    for (int nt = 0; nt < 2; ++nt) {
      #pragma unroll
      for (int kk = 0; kk < 2; ++kk) {
        acc[rt][nt] = __builtin_amdgcn_mfma_f32_16x16x32_bf16(ah[kk], bh[nt][kk], acc[rt][nt], 0, 0, 0);
        acc[rt][nt] = __builtin_amdgcn_mfma_f32_16x16x32_bf16(ah[kk], bl[nt][kk], acc[rt][nt], 0, 0, 0);
        acc[rt][nt] = __builtin_amdgcn_mfma_f32_16x16x32_bf16(al[kk], bh[nt][kk], acc[rt][nt], 0, 0, 0);
      }
    }
  }

  #pragma unroll
  for (int nt = 0; nt < 2; ++nt) {
    int col = wv * 32 + nt * 16 + lr;
    float bias = bin[col];
    #pragma unroll
    for (int rt = 0; rt < 4; ++rt) {
      #pragma unroll
      for (int r = 0; r < 4; ++r) {
        int node = nb + rt * 16 + lg * 4 + r;
        if (node < NN)
          hf[(size_t)node * 128 + col] = fmaxf(acc[rt][nt][r] + bias, 0.f);
      }
    }
  }
}

// ---------- per-NODE message MLP + fused BN-apply; LDS granule-staged A ----------
// Stage: each element touched exactly once; h_new = BN(hgru)+h_old -> hf_out
// write + split8 -> LDS granules. Compute: lane-linear reads, conflict-free.
// NOTE: hgru (read) may alias R (write): reads are in stage phase, writes in
// epilogue, and both touch only this block's 64 rows -> safe.
__global__ __launch_bounds__(256) void k_relu1(
    const float* __restrict__ hgru, const float* __restrict__ bnsc,
    const float* __restrict__ bnsh, const float* __restrict__ hf_in,
    float* __restrict__ hf_out,
    const u16* __restrict__ W1h, const u16* __restrict__ W1l,
    const float* __restrict__ b1, float* R, int fuse_bn) {
  __shared__ bf16x8 ghx[1024], glx[1024];   // 16KB + 16KB
  const int t = threadIdx.x;
  const int wv = t >> 6, ln = t & 63;
  const int lr = ln & 15, lg = ln >> 4;
  const int nb = blockIdx.x * 64;

  // ---- stage: thread t handles granules rt*256+t (rt=0..3) ----
  #pragma unroll
  for (int rt = 0; rt < 4; ++rt) {
    int row = nb + rt * 16 + (ln & 15);
    int rc = min(row, NN - 1);
    int kcol = wv * 32 + (ln >> 4) * 8;
    const float* hp = hf_in + (size_t)rc * 128 + kcol;
    float v[8];
    if (fuse_bn) {
      const float* gp = hgru + (size_t)rc * 128 + kcol;
      float4 g0 = *(const float4*)gp, g1 = *(const float4*)(gp + 4);
      float4 h0 = *(const float4*)hp, h1 = *(const float4*)(hp + 4);
      float4 sc0 = *(const float4*)(bnsc + kcol), sc1 = *(const float4*)(bnsc + kcol + 4);
      float4 sh0 = *(const float4*)(bnsh + kcol), sh1 = *(const float4*)(bnsh + kcol + 4);
      v[0] = g0.x * sc0.x + sh0.x + h0.x;
      v[1] = g0.y * sc0.y + sh0.y + h0.y;
      v[2] = g0.z * sc0.z + sh0.z + h0.z;
      v[3] = g0.w * sc0.w + sh0.w + h0.w;
      v[4] = g1.x * sc1.x + sh1.x + h1.x;
      v[5] = g1.y * sc1.y + sh1.y + h1.y;
      v[6] = g1.z * sc1.z + sh1.z + h1.z;
      v[7] = g1.w * sc1.w + sh1.w + h1.w;
      if (row < NN) {
        float* op = hf_out + (size_t)row * 128 + kcol;
        *(float4*)op = make_float4(v[0], v[1], v[2], v[3]);
        *(float4*)(op + 4) = make_float4(v[4], v[5], v[6], v[7]);
      }
    } else {
      float4 h0 = *(const float4*)hp, h1 = *(const float4*)(hp + 4);
      v[0] = h0.x; v[1] = h0.y; v[2] = h0.z; v[3] = h0.w;
      v[4] = h1.x; v[5] = h1.y; v[6] = h1.z; v[7] = h1.w;
    }
    bf16x8 h8, l8;
    split8v(v, h8, l8);
    ghx[rt * 256 + t] = h8;
    glx[rt * 256 + t] = l8;
  }
  __syncthreads();

  // B frags in registers (weights L2-hot, identical across blocks)
  bf16x8 bh[2][4], bl[2][4];
  #pragma unroll
  for (int nt = 0; nt < 2; ++nt) {
    size_t wb = (size_t)(wv * 32 + nt * 16 + lr) * 128 + lg * 8;
    #pragma unroll
    for (int kk = 0; kk < 4; ++kk) {
      bh[nt][kk] = *(const bf16x8*)(W1h + wb + kk * 32);
      bl[nt][kk] = *(const bf16x8*)(W1l + wb + kk * 32);
    }
  }

  f32x4 acc[4][2];
  #pragma unroll
  for (int rt = 0; rt < 4; ++rt)
    #pragma unroll
    for (int nt = 0; nt < 2; ++nt)
      acc[rt][nt] = (f32x4){0.f, 0.f, 0.f, 0.f};

  #pragma unroll
  for (int rt = 0; rt < 4; ++rt) {
    bf16x8 ah[4], al[4];
    #pragma unroll
    for (int kk = 0; kk < 4; ++kk) {
      ah[kk] = ghx[(rt * 4 + kk) * 64 + ln];
      al[kk] = glx[(rt * 4 + kk) * 64 + ln];
    }
    #pragma unroll
    for (int nt = 0; nt < 2; ++nt) {
      #pragma unroll
      for (int kk = 0; kk < 4; ++kk) {
        acc[rt][nt] = __builtin_amdgcn_mfma_f32_16x16x32_bf16(ah[kk], bh[nt][kk], acc[rt][nt], 0, 0, 0);
        acc[rt][nt] = __builtin_amdgcn_mfma_f32_16x16x32_bf16(ah[kk], bl[nt][kk], acc[rt][nt], 0, 0, 0);
        acc[rt][nt] = __builtin_amdgcn_mfma_f32_16x16x32_bf16(al[kk], bh[nt][kk], acc[rt][nt], 0, 0, 0);
      }
    }
  }

  #pragma unroll
  for (int nt = 0; nt < 2; ++nt) {
    int col = wv * 32 + nt * 16 + lr;
    float bias = b1[col];
    #pragma unroll
    for (int rt = 0; rt < 4; ++rt) {
      #pragma unroll
      for (int r = 0; r < 4; ++r) {
        int node = nb + rt * 16 + lg * 4 + r;
        if (node < NN)
          R[(size_t)node * 128 + col] = fmaxf(acc[rt][nt][r] + bias, 0.f);
      }
    }
  }
}

#define MFMA3(ACC, AH, AL, BH, BL)                                             \
  ACC = __builtin_amdgcn_mfma_f32_16x16x32_bf16(AH, BH, ACC, 0, 0, 0);         \
  ACC = __builtin_amdgcn_mfma_f32_16x16x32_bf16(AH, BL, ACC, 0, 0, 0);         \
  ACC = __builtin_amdgcn_mfma_f32_16x16x32_bf16(AL, BH, ACC, 0, 0, 0);

// ---------- FUSED aggregation + GRU + BN partial stats ----------
// Phase 1 (wave-private): CSR-gather this wave's 16 node rows from R
// (bit-identical 4-ILP order to old k_aggr) into padded LDS tile [16][132].
// Phase 2: A-fragments from LDS (2-way aliasing = free), split in-register.
// Phase 3: r12's proven nt-loop (global_load_lds weight staging).
// LDS union: aggT (33KB, dead after phase 2) aliases weight buffer (48KB);
// the first nt-iteration's __syncthreads() fences the alias.
__global__ __launch_bounds__(256) void k_gru(
    const float* __restrict__ R, const float* __restrict__ hf,
    const int* __restrict__ es, const int* __restrict__ rowend,
    const u16* __restrict__ pW,
    const float* __restrict__ c2, const float* __restrict__ bih,
    const float* __restrict__ bhh, const int* __restrict__ degi,
    float* __restrict__ hgru, double* __restrict__ partials) {
  union SM {
    float aggT[4][16][132];   // 33792 B
    uint4 w[12 * 256];        // 49152 B
  };
  __shared__ SM sm;
  u16* wlds = (u16*)sm.w;
  const int t = threadIdx.x;
  const int ln = t & 63, wv = t >> 6;
  const int lr = ln & 15, lg = ln >> 4;
  const int nb = blockIdx.x * 64 + wv * 16;
  const int rowc = min(nb + lr, NN - 1);
  const size_t prow = ((size_t)blockIdx.x * 4 + wv) * 256;

  // ---- phase 1: gather 16 nodes (wave-private; no block barrier needed) ----
  {
    const int cp = ln * 2;
    #pragma unroll 1
    for (int i = 0; i < 16; ++i) {
      int nc = min(nb + i, NN - 1);
      int k0 = (nc == 0) ? 0 : rowend[nc - 1];
      int k1 = rowend[nc];
      float sx0 = 0.f, sx1 = 0.f, sx2 = 0.f, sx3 = 0.f;
      float sy0 = 0.f, sy1 = 0.f, sy2 = 0.f, sy3 = 0.f;
      int k = k0;
      for (; k + 4 <= k1; k += 4) {
        int e0 = es[k], e1 = es[k + 1], e2 = es[k + 2], e3 = es[k + 3];
        float2 v0 = *(const float2*)(R + (size_t)e0 * 128 + cp);
        float2 v1 = *(const float2*)(R + (size_t)e1 * 128 + cp);
        float2 v2 = *(const float2*)(R + (size_t)e2 * 128 + cp);
        float2 v3 = *(const float2*)(R + (size_t)e3 * 128 + cp);
        sx0 += v0.x; sy0 += v0.y;
        sx1 += v1.x; sy1 += v1.y;
        sx2 += v2.x; sy2 += v2.y;
        sx3 += v3.x; sy3 += v3.y;
      }
      for (; k < k1; ++k) {
        float2 v = *(const float2*)(R + (size_t)es[k] * 128 + cp);
        sx0 += v.x; sy0 += v.y;
      }
      sm.aggT[wv][i][cp] = (sx0 + sx1) + (sx2 + sx3);
      sm.aggT[wv][i][cp + 1] = (sy0 + sy1) + (sy2 + sy3);
    }
  }

  // ---- phase 2: A-fragments (aggr from LDS, h from global) ----
  bf16x8 Aah[4], Aal[4], Ahh[4], Ahl[4];
  #pragma unroll
  for (int kk = 0; kk < 4; ++kk) {
    int c0 = kk * 32 + lg * 8;
    float v[8];
    #pragma unroll
    for (int j = 0; j < 8; ++j) v[j] = sm.aggT[wv][lr][c0 + j];
    split8v(v, Aah[kk], Aal[kk]);
    split8(hf + (size_t)rowc * 128 + c0, Ahh[kk], Ahl[kk]);
  }

  float degs[4];
  int noderow[4];
  #pragma unroll
  for (int r = 0; r < 4; ++r) {
    noderow[r] = min(nb + lg * 4 + r, NN - 1);
    degs[r] = (float)degi[noderow[r]];
  }

  // ---- phase 3: nt loop (r12-proven). First barrier fences aggT alias. ----
  #pragma unroll 1
  for (int nt = 0; nt < 8; ++nt) {
    const int col = nt * 16 + lr;

    float fh[4];
    #pragma unroll
    for (int r = 0; r < 4; ++r)
      fh[r] = hf[(size_t)noderow[r] * 128 + col];

    __syncthreads();   // all waves done with prior reads (aggT at nt=0)
    #pragma unroll
    for (int j = 0; j < 12; ++j) {
      size_t gidx = (size_t)nt * 3072 + j * 256 + t;   // granule index
      gload16(pW + gidx * 8, wlds + (size_t)(j * 256 + t) * 8);
    }
    __syncthreads();   // vmcnt drained by compiler before barrier

    f32x4 ar = (f32x4){0.f, 0.f, 0.f, 0.f};
    f32x4 az = ar, ai = ar, an = ar;
    #pragma unroll
    for (int kk = 0; kk < 4; ++kk) {
      const bf16x8* wb = (const bf16x8*)wlds + kk * 64 + ln;   // lane-linear
      bf16x8 brh = wb[0 * 256];
      bf16x8 brl = wb[1 * 256];
      bf16x8 crh = wb[2 * 256];
      bf16x8 crl = wb[3 * 256];
      MFMA3(ar, Aah[kk], Aal[kk], brh, brl)
      MFMA3(ar, Ahh[kk], Ahl[kk], crh, crl)
      bf16x8 bzh = wb[4 * 256];
      bf16x8 bzl = wb[5 * 256];
      bf16x8 czh = wb[6 * 256];
      bf16x8 czl = wb[7 * 256];
      MFMA3(az, Aah[kk], Aal[kk], bzh, bzl)
      MFMA3(az, Ahh[kk], Ahl[kk], czh, czl)
      bf16x8 bnh = wb[8 * 256];
      bf16x8 bnl = wb[9 * 256];
      bf16x8 cnh = wb[10 * 256];
      bf16x8 cnl = wb[11 * 256];
      MFMA3(ai, Aah[kk], Aal[kk], bnh, bnl)
      MFMA3(an, Ahh[kk], Ahl[kk], cnh, cnl)
    }

    float c2r = c2[col], c2z = c2[128 + col], c2n = c2[256 + col];
    float br = bih[col] + bhh[col];
    float bz = bih[128 + col] + bhh[128 + col];
    float bin_ = bih[256 + col], bhn = bhh[256 + col];
    double s = 0.0, s2 = 0.0;
    #pragma unroll
    for (int r = 0; r < 4; ++r) {
      int node = nb + lg * 4 + r;
      bool valid = node < NN;
      float d = degs[r];
      float sr = ar[r] + d * c2r + br;
      float sz = az[r] + d * c2z + bz;
      float rg = 1.f / (1.f + __expf(-sr));
      float zg = 1.f / (1.f + __expf(-sz));
      float ngin = ai[r] + d * c2n + bin_ + rg * (an[r] + bhn);
      float e2 = __expf(-2.f * fabsf(ngin));
      float ng = __builtin_copysignf((1.f - e2) / (1.f + e2), ngin);
      float hn = (1.f - zg) * ng + zg * fh[r];
      if (valid) {
        hgru[(size_t)node * 128 + col] = hn;
        s += (double)hn;
        s2 += (double)hn * (double)hn;
      }
    }
    s += __shfl_xor(s, 16);  s += __shfl_xor(s, 32);
    s2 += __shfl_xor(s2, 16); s2 += __shfl_xor(s2, 32);
    if (lg == 0) {
      partials[prow + col] = s;
      partials[prow + 128 + col] = s2;
    }
  }
}

// ---------- BN stats reduction (deterministic, f64) ----------
__global__ void k_bnred_a(const double* __restrict__ partials, double* __restrict__ interm) {
  int b = blockIdx.x;       // 64
  int c = threadIdx.x;      // 256
  double s = 0.0;
  int i0 = b * 98, i1 = min(i0 + 98, NPART);
  for (int i = i0; i < i1; ++i) s += partials[(size_t)i * 256 + c];
  interm[b * 256 + c] = s;
}
__global__ void k_bnred_b(const double* __restrict__ interm, const float* __restrict__ gamma,
                          const float* __restrict__ beta, float* __restrict__ bnsc,
                          float* __restrict__ bnsh) {
  int c = threadIdx.x;      // 128
  double s = 0.0, s2 = 0.0;
  for (int i = 0; i < 64; ++i) {
    s += interm[i * 256 + c];
    s2 += interm[i * 256 + 128 + c];
  }
  double mu = s / (double)NN;
  double var = s2 / (double)NN - mu * mu;
  float sc = (float)((double)gamma[c] / sqrt(var + (double)BN_EPS));
  bnsc[c] = sc;
  bnsh[c] = (float)((double)beta[c] - mu * (double)sc);
}

// ---------- final BN apply + residual (last layer only; in-place elementwise) ----------
__global__ void k_bnapply(const float* __restrict__ hgru, const float* __restrict__ bnsc,
                          const float* __restrict__ bnsh, float* __restrict__ hf) {
  int i = blockIdx.x * 256 + threadIdx.x;  // NN*HH/4 exact
  int c4 = i & 31;
  float4 g = ((const float4*)hgru)[i];
  float4 sc = ((const float4*)bnsc)[c4];
  float4 sh = ((const float4*)bnsh)[c4];
  float4 h = ((const float4*)hf)[i];
  float4 o;
  o.x = g.x * sc.x + sh.x + h.x;
  o.y = g.y * sc.y + sh.y + h.y;
  o.z = g.z * sc.z + sh.z + h.z;
  o.w = g.w * sc.w + sh.w + h.w;
  ((float4*)hf)[i] = o;
}

// ---------- output ----------
__global__ void k_out(const float* __restrict__ hf, const float* __restrict__ wout,
                      const float* __restrict__ bout, float* __restrict__ out) {
  int ln = threadIdx.x & 63;
  int n = blockIdx.x * 4 + (threadIdx.x >> 6);
  float2 w = ((const float2*)wout)[ln];
  float2 v = ((const float2*)(hf + (size_t)n * 128))[ln];
  float s = v.x * w.x + v.y * w.y;
  #pragma unroll
  for (int d = 32; d > 0; d >>= 1) s += __shfl_xor(s, d);
  if (ln == 0) out[n] = s + bout[0];
}

extern "C" void kernel_launch(void* const* d_in, const int* in_sizes, int n_in,
                              void* d_out, int out_size, void* d_ws, size_t ws_size,
                              hipStream_t stream) {
  const float* x = (const float*)d_in[0];
  const int* eraw = (const int*)d_in[1];
  const float* Win = (const float*)d_in[2];
  const float* bin = (const float*)d_in[3];
  const float* mW1 = (const float*)d_in[4];
  const float* mb1 = (const float*)d_in[5];
  const float* mW2 = (const float*)d_in[6];
  const float* mb2 = (const float*)d_in[7];
  const float* Wih = (const float*)d_in[8];
  const float* bih = (const float*)d_in[9];
  const float* Whh = (const float*)d_in[10];
  const float* bhh = (const float*)d_in[11];
  const float* gamma = (const float*)d_in[12];
  const float* beta = (const float*)d_in[13];
  const float* wout = (const float*)d_in[14];
  const float* bout = (const float*)d_in[15];
  float* out = (float*)d_out;

  char* ws = (char*)d_ws;
  size_t off = 0;
  auto carve = [&](size_t b) -> char* {
    char* p = ws + off;
    off = (off + b + 255) & ~(size_t)255;
    return p;
  };
  // 4 big buffers (51.2 MB each), lifetime-aliased:
  //   Hbuf[l&1]       : h_l (ping-pong)
  //   RG[l&1]         : R_l  (read by fused k_gru's gather; also holds
  //                     hgru_{l-1} which k_relu1 reads before writing R_l --
  //                     same-block-ownership read-before-write, safe)
  //   RG[(l+1)&1]     : hgru_l (written by k_gru; distinct from R_l)
  float* Hbuf0 = (float*)carve(sizeof(float) * NN * HH);
  float* Hbuf1 = (float*)carve(sizeof(float) * NN * HH);
  float* RG0 = (float*)carve(sizeof(float) * NN * HH);
  float* RG1 = (float*)carve(sizeof(float) * NN * HH);
  int* es = (int*)carve(sizeof(int) * EE);
  int* idxflag = (int*)carve(sizeof(int) * 64);
  int* degi = (int*)carve(sizeof(int) * NN);
  int* curs = (int*)carve(sizeof(int) * NN);
  int* bsum = (int*)carve(sizeof(int) * SCAN_BLK);
  double* partials = (double*)carve(sizeof(double) * NPART * 256);
  double* interm = (double*)carve(sizeof(double) * 64 * 256);
  float* bnsc = (float*)carve(sizeof(float) * 128);
  float* bnsh = (float*)carve(sizeof(float) * 128);
  u16* W1h = (u16*)carve(sizeof(u16) * 4 * HH * HH);
  u16* W1l = (u16*)carve(sizeof(u16) * 4 * HH * HH);
  float* Wff = (float*)carve(sizeof(float) * 4 * 384 * HH);
  u16* pW = (u16*)carve(sizeof(u16) * 4 * 24576 * 8);   // nt-major packed GRU weights
  float* c2 = (float*)carve(sizeof(float) * 4 * 384);
  // total ~228 MB (round-5's 247 MB fit; round-7's 292 MB crashed)

  float* Hbuf[2] = {Hbuf0, Hbuf1};
  float* RG[2] = {RG0, RG1};

  // ---- index dtype probe (no extracted copy; CSR kernels read eraw) ----
  k_idx_probe<<<1, 64, 0, stream>>>(eraw, idxflag);

  // ---- CSR build (dst-sorted edges; curs ends as row-end array) ----
  hipMemsetAsync(degi, 0, sizeof(int) * NN, stream);
  k_hist<<<(EE + 255) / 256, 256, 0, stream>>>(eraw, idxflag, degi);
  k_scan1<<<SCAN_BLK, 256, 0, stream>>>(degi, curs, bsum);
  k_scan2<<<1, 64, 0, stream>>>(bsum);
  k_scan3<<<SCAN_BLK, 256, 0, stream>>>(curs, bsum);
  k_scatter<<<(EE + 255) / 256, 256, 0, stream>>>(eraw, idxflag, curs, es);

  // ---- weight prep ----
  k_split<<<(4 * HH * HH / 4) / 256, 256, 0, stream>>>(mW1, W1h, W1l, 4 * HH * HH / 4);
  k_fuse_wf<<<4 * 384, 128, 0, stream>>>(Wih, mW2, Wff);
  k_packsplit2<<<384, 256, 0, stream>>>(Wff, Whh, pW);
  k_c2<<<6, 256, 0, stream>>>(Wih, mb2, c2);

  // ---- state init: h_0 -> Hbuf[0] ----
  k_inproj2<<<(NN + 63) / 64, 256, 0, stream>>>(x, Win, bin, Hbuf[0]);

  for (int l = 0; l < LL; ++l) {
    const float* h_old = Hbuf[(l == 0) ? 0 : ((l - 1) & 1)];  // h_{l-1}
    float* h_cur = Hbuf[l & 1];                               // h_l
    float* Rbuf = RG[l & 1];                                  // R_l
    const float* hgru_prev = RG[l & 1];                       // hgru_{l-1} (same buf as R_l; safe)
    float* hgru_cur = RG[(l + 1) & 1];                        // hgru_l
    // R = relu(h_l @ W1^T + b1); for l>0 also materializes h_l = BN(hgru_{l-1})+h_{l-1}
    k_relu1<<<(NN + 63) / 64, 256, 0, stream>>>(
        hgru_prev, bnsc, bnsh, h_old, h_cur,
        W1h + (size_t)l * HH * HH, W1l + (size_t)l * HH * HH,
        mb1 + l * HH, Rbuf, l > 0 ? 1 : 0);
    // fused gather + GRU
    k_gru<<<(NN + 63) / 64, 256, 0, stream>>>(
        Rbuf, h_cur, es, curs, pW + (size_t)l * 24576 * 8,
        c2 + l * 384, bih + l * 384, bhh + l * 384, degi, hgru_cur, partials);
    k_bnred_a<<<64, 256, 0, stream>>>(partials, interm);
    k_bnred_b<<<1, 128, 0, stream>>>(interm, gamma + l * HH, beta + l * HH, bnsc, bnsh);
  }
  // final h_4 = BN(hgru_3) + h_3 ; hgru_3 in RG[(LL)&1] = RG[0], h_3 in Hbuf[1]
  k_bnapply<<<(NN * HH / 4) / 256, 256, 0, stream>>>(RG[LL & 1], bnsc, bnsh,
                                                     Hbuf[(LL - 1) & 1]);
  k_out<<<NN / 4, 256, 0, stream>>>(Hbuf[(LL - 1) & 1], wout, bout, out);
}

// Round 16
// 1499.161 us; speedup vs baseline: 1.2734x; 1.2734x over previous
//
#include <hip/hip_runtime.h>
#include <hip/hip_bf16.h>

#define NN 100000
#define EE 1600000
#define HH 128
#define LL 4
#define BN_EPS 1e-5f
#define NPART 6252       // 1563 blocks * 4 waves (k_gru geometry)
#define SCAN_BLK 391     // ceil(100000/256)

typedef __attribute__((ext_vector_type(8))) short bf16x8;
typedef __attribute__((ext_vector_type(4))) float f32x4;
typedef unsigned short u16;

static __device__ __forceinline__ u16 f2bf(float f) {
  unsigned u = __float_as_uint(f);
  u += 0x7FFF + ((u >> 16) & 1);   // RNE
  return (u16)(u >> 16);
}
static __device__ __forceinline__ float bf2f(u16 h) {
  return __uint_as_float(((unsigned)h) << 16);
}
static __device__ __forceinline__ void split8v(const float* v, bf16x8& hi, bf16x8& lo) {
  #pragma unroll
  for (int i = 0; i < 8; ++i) {
    u16 h = f2bf(v[i]);
    hi[i] = (short)h;
    lo[i] = (short)f2bf(v[i] - bf2f(h));
  }
}
// split 8 consecutive f32 (from memory) into hi/lo bf16x8 fragments
static __device__ __forceinline__ void split8(const float* p, bf16x8& hi, bf16x8& lo) {
  float4 a = *(const float4*)p, b = *(const float4*)(p + 4);
  float v[8] = {a.x, a.y, a.z, a.w, b.x, b.y, b.z, b.w};
  split8v(v, hi, lo);
}

// ---------- async global->LDS, 16B per lane (CK-style addrspace casts) ----------
static __device__ __forceinline__ void gload16(const void* g, void* l) {
  __attribute__((address_space(3))) unsigned* lp =
      (__attribute__((address_space(3))) unsigned*)(reinterpret_cast<uintptr_t>(l));
  const __attribute__((address_space(1))) unsigned* gp =
      (const __attribute__((address_space(1))) unsigned*)(reinterpret_cast<uintptr_t>(g));
  __builtin_amdgcn_global_load_lds(gp, lp, 16, 0, 0);
}

// ---------- split f32 -> (hi, lo) bf16 pair (row-major; W1 only) ----------
__global__ void k_split(const float* __restrict__ src, u16* __restrict__ hi,
                        u16* __restrict__ lo, int n4) {
  int i = blockIdx.x * 256 + threadIdx.x;
  if (i >= n4) return;
  float4 v = ((const float4*)src)[i];
  ushort4 h_, l_;
  h_.x = f2bf(v.x); l_.x = f2bf(v.x - bf2f(h_.x));
  h_.y = f2bf(v.y); l_.y = f2bf(v.y - bf2f(h_.y));
  h_.z = f2bf(v.z); l_.z = f2bf(v.z - bf2f(h_.z));
  h_.w = f2bf(v.w); l_.w = f2bf(v.w - bf2f(h_.w));
  ((ushort4*)hi)[i] = h_;
  ((ushort4*)lo)[i] = l_;
}

// ---------- pack GRU weights into nt-major MFMA-linear granule layout ----------
// pW[l][nt][tile=g*4+a][gr=kk*64+lane] (16B granules). Content: array a
// (0=Wf hi,1=Wf lo,2=Whh hi,3=Whh lo), gate g, row g*128+nt*16+(lane&15),
// kcol kk*32+(lane>>4)*8. Wave reads/stages 64 consecutive granules.
__global__ void k_packsplit2(const float* __restrict__ Wff, const float* __restrict__ Whh,
                             u16* __restrict__ pW) {
  int gid = blockIdx.x * 256 + threadIdx.x;   // 4*8*12*256 = 98304
  if (gid >= 98304) return;
  int gr = gid & 255;
  int lane = gr & 63, kk = gr >> 6;
  int rest = gid >> 8;          // 0..383
  int tile = rest % 12;
  int nt = (rest / 12) & 7;
  int l = rest / 96;
  int g = tile >> 2, a = tile & 3;
  int row = g * 128 + nt * 16 + (lane & 15);
  int kcol = kk * 32 + (lane >> 4) * 8;
  const float* src = ((a < 2) ? Wff : Whh) + ((size_t)l * 384 + row) * 128 + kcol;
  bf16x8 h8, l8;
  split8(src, h8, l8);
  *(bf16x8*)(pW + (size_t)gid * 8) = (a & 1) ? l8 : h8;
}

// ---------- edge index dtype probe ----------
__global__ void k_idx_probe(const int* __restrict__ e32, int* __restrict__ flag) {
  if (threadIdx.x == 0 && blockIdx.x == 0) {
    int z = e32[1] | e32[3] | e32[5] | e32[7] | e32[9] | e32[11];
    flag[0] = (z == 0) ? 1 : 0;   // 1 => int64 payload
  }
}

// ---------- CSR build (reads raw edge buffer, no extracted copy) ----------
__global__ void k_hist(const int* __restrict__ e32, const int* __restrict__ flag,
                       int* __restrict__ degi) {
  int i = blockIdx.x * 256 + threadIdx.x;
  if (i < EE) {
    int d = flag[0] ? e32[2 * (size_t)(EE + i)] : e32[EE + i];
    atomicAdd(&degi[d], 1);
  }
}
__global__ void k_scan1(const int* __restrict__ degi, int* __restrict__ curs,
                        int* __restrict__ bsum) {
  __shared__ int s[256];
  int t = threadIdx.x;
  int i = blockIdx.x * 256 + t;
  int v = (i < NN) ? degi[i] : 0;
  s[t] = v;
  __syncthreads();
  #pragma unroll
  for (int o = 1; o < 256; o <<= 1) {
    int u = (t >= o) ? s[t - o] : 0;
    __syncthreads();
    s[t] += u;
    __syncthreads();
  }
  if (i < NN) curs[i] = s[t] - v;     // exclusive
  if (t == 255) bsum[blockIdx.x] = s[255];
}
__global__ void k_scan2(int* __restrict__ bsum) {
  if (threadIdx.x == 0 && blockIdx.x == 0) {
    int run = 0;
    for (int b = 0; b < SCAN_BLK; ++b) { int v = bsum[b]; bsum[b] = run; run += v; }
  }
}
__global__ void k_scan3(int* __restrict__ curs, const int* __restrict__ bsum) {
  int i = blockIdx.x * 256 + threadIdx.x;
  if (i < NN) curs[i] += bsum[blockIdx.x];
}
__global__ void k_scatter(const int* __restrict__ e32, const int* __restrict__ flag,
                          int* __restrict__ curs, int* __restrict__ es) {
  int i = blockIdx.x * 256 + threadIdx.x;
  if (i < EE) {
    int f = flag[0];
    int s = f ? e32[2 * (size_t)i] : e32[i];
    int d = f ? e32[2 * (size_t)(EE + i)] : e32[EE + i];
    int p = atomicAdd(&curs[d], 1);
    es[p] = s;
  }
  // after this kernel: curs[n] == row end of node n (exclusive)
}

// ---------- Wf = Wih @ W2 (f32) ----------
__global__ void k_fuse_wf(const float* __restrict__ Wih, const float* __restrict__ W2,
                          float* __restrict__ Wff) {
  int li = blockIdx.x;             // 0..4*384-1
  int l = li / 384;
  int j = threadIdx.x;             // 0..127
  const float* wr = Wih + (size_t)li * 128;
  const float* w2 = W2 + (size_t)l * 128 * 128;
  float s = 0.f;
  #pragma unroll 8
  for (int k = 0; k < 128; ++k) s += wr[k] * w2[k * 128 + j];
  Wff[(size_t)li * 128 + j] = s;
}

// ---------- c2 = Wih @ b2 ----------
__global__ void k_c2(const float* __restrict__ Wih, const float* __restrict__ b2,
                     float* __restrict__ c2) {
  int gid = blockIdx.x * 256 + threadIdx.x;
  if (gid >= 4 * 384) return;
  int l = gid / 384;
  const float* wr = Wih + (size_t)gid * 128;
  const float* br = b2 + (size_t)l * 128;
  float s = 0.f;
  #pragma unroll 8
  for (int k = 0; k < 128; ++k) s += wr[k] * br[k];
  c2[gid] = s;
}

// ---------- input projection via MFMA (bf16x3): h = relu(x @ Win^T + bin) ----------
__global__ __launch_bounds__(256) void k_inproj2(
    const float* __restrict__ x, const float* __restrict__ Win,
    const float* __restrict__ bin, float* __restrict__ hf) {
  __shared__ u16 xh[64][72], xl[64][72];
  const int t = threadIdx.x;
  const int wv = t >> 6, ln = t & 63;
  const int lr = ln & 15, lg = ln >> 4;
  const int nb = blockIdx.x * 64;

  #pragma unroll
  for (int it = 0; it < 4; ++it) {
    int idx = t + it * 256;            // 0..1023 : 64 rows x 16 float4
    int row = idx >> 4, c4 = idx & 15;
    int node = nb + row;
    float4 v = (node < NN) ? ((const float4*)(x + (size_t)node * 64))[c4]
                           : make_float4(0.f, 0.f, 0.f, 0.f);
    ushort4 h_, l_;
    h_.x = f2bf(v.x); l_.x = f2bf(v.x - bf2f(h_.x));
    h_.y = f2bf(v.y); l_.y = f2bf(v.y - bf2f(h_.y));
    h_.z = f2bf(v.z); l_.z = f2bf(v.z - bf2f(h_.z));
    h_.w = f2bf(v.w); l_.w = f2bf(v.w - bf2f(h_.w));
    *(ushort4*)&xh[row][c4 * 4] = h_;
    *(ushort4*)&xl[row][c4 * 4] = l_;
  }
  __syncthreads();

  f32x4 acc[4][2];
  #pragma unroll
  for (int rt = 0; rt < 4; ++rt)
    #pragma unroll
    for (int nt = 0; nt < 2; ++nt)
      acc[rt][nt] = (f32x4){0.f, 0.f, 0.f, 0.f};

  bf16x8 bh[2][2], bl[2][2];
  #pragma unroll
  for (int nt = 0; nt < 2; ++nt) {
    int c = wv * 32 + nt * 16 + lr;
    #pragma unroll
    for (int kk = 0; kk < 2; ++kk)
      split8(Win + (size_t)c * 64 + kk * 32 + lg * 8, bh[nt][kk], bl[nt][kk]);
  }

  #pragma unroll
  for (int rt = 0; rt < 4; ++rt) {
    bf16x8 ah[2], al[2];
    #pragma unroll
    for (int kk = 0; kk < 2; ++kk) {
      ah[kk] = *(const bf16x8*)(&xh[rt * 16 + lr][kk * 32 + lg * 8]);
      al[kk] = *(const bf16x8*)(&xl[rt * 16 + lr][kk * 32 + lg * 8]);
    }
    #pragma unroll
    for (int nt = 0; nt < 2; ++nt) {
      #pragma unroll
      for (int kk = 0; kk < 2; ++kk) {
        acc[rt][nt] = __builtin_amdgcn_mfma_f32_16x16x32_bf16(ah[kk], bh[nt][kk], acc[rt][nt], 0, 0, 0);
        acc[rt][nt] = __builtin_amdgcn_mfma_f32_16x16x32_bf16(ah[kk], bl[nt][kk], acc[rt][nt], 0, 0, 0);
        acc[rt][nt] = __builtin_amdgcn_mfma_f32_16x16x32_bf16(al[kk], bh[nt][kk], acc[rt][nt], 0, 0, 0);
      }
    }
  }

  #pragma unroll
  for (int nt = 0; nt < 2; ++nt) {
    int col = wv * 32 + nt * 16 + lr;
    float bias = bin[col];
    #pragma unroll
    for (int rt = 0; rt < 4; ++rt) {
      #pragma unroll
      for (int r = 0; r < 4; ++r) {
        int node = nb + rt * 16 + lg * 4 + r;
        if (node < NN)
          hf[(size_t)node * 128 + col] = fmaxf(acc[rt][nt][r] + bias, 0.f);
      }
    }
  }
}

// ---------- per-NODE message MLP + fused BN-apply; LDS granule-staged A ----------
// Stage phase (once per block, each element touched exactly once):
//   h_new = hgru*bnsc + bnsh + h_old (fuse_bn) -> hf_out write + split8 -> LDS
// granule g = (rt*4+kk)*64+lane holds row rt*16+(lane&15), kcols kk*32+(lane>>4)*8.
// Compute phase: wave reads 64 consecutive granules -> conflict-free.
__global__ __launch_bounds__(256) void k_relu1(
    const float* __restrict__ hgru, const float* __restrict__ bnsc,
    const float* __restrict__ bnsh, const float* __restrict__ hf_in,
    float* __restrict__ hf_out,
    const u16* __restrict__ W1h, const u16* __restrict__ W1l,
    const float* __restrict__ b1, float* __restrict__ R, int fuse_bn) {
  __shared__ bf16x8 ghx[1024], glx[1024];   // 16KB + 16KB
  const int t = threadIdx.x;
  const int wv = t >> 6, ln = t & 63;
  const int lr = ln & 15, lg = ln >> 4;
  const int nb = blockIdx.x * 64;

  // ---- stage: thread t handles granules rt*256+t (rt=0..3) ----
  #pragma unroll
  for (int rt = 0; rt < 4; ++rt) {
    int row = nb + rt * 16 + (ln & 15);
    int rc = min(row, NN - 1);
    int kcol = wv * 32 + (ln >> 4) * 8;
    const float* hp = hf_in + (size_t)rc * 128 + kcol;
    float v[8];
    if (fuse_bn) {
      const float* gp = hgru + (size_t)rc * 128 + kcol;
      float4 g0 = *(const float4*)gp, g1 = *(const float4*)(gp + 4);
      float4 h0 = *(const float4*)hp, h1 = *(const float4*)(hp + 4);
      float4 sc0 = *(const float4*)(bnsc + kcol), sc1 = *(const float4*)(bnsc + kcol + 4);
      float4 sh0 = *(const float4*)(bnsh + kcol), sh1 = *(const float4*)(bnsh + kcol + 4);
      v[0] = g0.x * sc0.x + sh0.x + h0.x;
      v[1] = g0.y * sc0.y + sh0.y + h0.y;
      v[2] = g0.z * sc0.z + sh0.z + h0.z;
      v[3] = g0.w * sc0.w + sh0.w + h0.w;
      v[4] = g1.x * sc1.x + sh1.x + h1.x;
      v[5] = g1.y * sc1.y + sh1.y + h1.y;
      v[6] = g1.z * sc1.z + sh1.z + h1.z;
      v[7] = g1.w * sc1.w + sh1.w + h1.w;
      if (row < NN) {
        float* op = hf_out + (size_t)row * 128 + kcol;
        *(float4*)op = make_float4(v[0], v[1], v[2], v[3]);
        *(float4*)(op + 4) = make_float4(v[4], v[5], v[6], v[7]);
      }
    } else {
      float4 h0 = *(const float4*)hp, h1 = *(const float4*)(hp + 4);
      v[0] = h0.x; v[1] = h0.y; v[2] = h0.z; v[3] = h0.w;
      v[4] = h1.x; v[5] = h1.y; v[6] = h1.z; v[7] = h1.w;
    }
    bf16x8 h8, l8;
    split8v(v, h8, l8);
    ghx[rt * 256 + t] = h8;
    glx[rt * 256 + t] = l8;
  }
  __syncthreads();

  // B frags in registers (weights L2-hot, identical across blocks)
  bf16x8 bh[2][4], bl[2][4];
  #pragma unroll
  for (int nt = 0; nt < 2; ++nt) {
    size_t wb = (size_t)(wv * 32 + nt * 16 + lr) * 128 + lg * 8;
    #pragma unroll
    for (int kk = 0; kk < 4; ++kk) {
      bh[nt][kk] = *(const bf16x8*)(W1h + wb + kk * 32);
      bl[nt][kk] = *(const bf16x8*)(W1l + wb + kk * 32);
    }
  }

  f32x4 acc[4][2];
  #pragma unroll
  for (int rt = 0; rt < 4; ++rt)
    #pragma unroll
    for (int nt = 0; nt < 2; ++nt)
      acc[rt][nt] = (f32x4){0.f, 0.f, 0.f, 0.f};

  #pragma unroll
  for (int rt = 0; rt < 4; ++rt) {
    bf16x8 ah[4], al[4];
    #pragma unroll
    for (int kk = 0; kk < 4; ++kk) {
      ah[kk] = ghx[(rt * 4 + kk) * 64 + ln];
      al[kk] = glx[(rt * 4 + kk) * 64 + ln];
    }
    #pragma unroll
    for (int nt = 0; nt < 2; ++nt) {
      #pragma unroll
      for (int kk = 0; kk < 4; ++kk) {
        acc[rt][nt] = __builtin_amdgcn_mfma_f32_16x16x32_bf16(ah[kk], bh[nt][kk], acc[rt][nt], 0, 0, 0);
        acc[rt][nt] = __builtin_amdgcn_mfma_f32_16x16x32_bf16(ah[kk], bl[nt][kk], acc[rt][nt], 0, 0, 0);
        acc[rt][nt] = __builtin_amdgcn_mfma_f32_16x16x32_bf16(al[kk], bh[nt][kk], acc[rt][nt], 0, 0, 0);
      }
    }
  }

  #pragma unroll
  for (int nt = 0; nt < 2; ++nt) {
    int col = wv * 32 + nt * 16 + lr;
    float bias = b1[col];
    #pragma unroll
    for (int rt = 0; rt < 4; ++rt) {
      #pragma unroll
      for (int r = 0; r < 4; ++r) {
        int node = nb + rt * 16 + lg * 4 + r;
        if (node < NN)
          R[(size_t)node * 128 + col] = fmaxf(acc[rt][nt][r] + bias, 0.f);
      }
    }
  }
}

// ---------- aggregation: aggr[n] = sum_{k in row(n)} R[es[k]], CSR, 4-way ILP ----------
__global__ __launch_bounds__(256) void k_aggr(
    const float* __restrict__ R, const int* __restrict__ es,
    const int* __restrict__ rowend, float* __restrict__ aggr) {
  const int t = threadIdx.x;
  const int node = blockIdx.x * 4 + (t >> 6);
  const int cp = (t & 63) * 2;
  if (node >= NN) return;
  const int k0 = (node == 0) ? 0 : rowend[node - 1];
  const int k1 = rowend[node];
  float sx0 = 0.f, sx1 = 0.f, sx2 = 0.f, sx3 = 0.f;
  float sy0 = 0.f, sy1 = 0.f, sy2 = 0.f, sy3 = 0.f;
  int k = k0;
  for (; k + 4 <= k1; k += 4) {
    int e0 = es[k], e1 = es[k + 1], e2 = es[k + 2], e3 = es[k + 3];
    float2 v0 = *(const float2*)(R + (size_t)e0 * 128 + cp);
    float2 v1 = *(const float2*)(R + (size_t)e1 * 128 + cp);
    float2 v2 = *(const float2*)(R + (size_t)e2 * 128 + cp);
    float2 v3 = *(const float2*)(R + (size_t)e3 * 128 + cp);
    sx0 += v0.x; sy0 += v0.y;
    sx1 += v1.x; sy1 += v1.y;
    sx2 += v2.x; sy2 += v2.y;
    sx3 += v3.x; sy3 += v3.y;
  }
  for (; k < k1; ++k) {
    float2 v = *(const float2*)(R + (size_t)es[k] * 128 + cp);
    sx0 += v.x; sy0 += v.y;
  }
  size_t o = (size_t)node * 128 + cp;
  aggr[o] = (sx0 + sx1) + (sx2 + sx3);
  aggr[o + 1] = (sy0 + sy1) + (sy2 + sy3);
}

#define MFMA3(ACC, AH, AL, BH, BL)                                             \
  ACC = __builtin_amdgcn_mfma_f32_16x16x32_bf16(AH, BH, ACC, 0, 0, 0);         \
  ACC = __builtin_amdgcn_mfma_f32_16x16x32_bf16(AH, BL, ACC, 0, 0, 0);         \
  ACC = __builtin_amdgcn_mfma_f32_16x16x32_bf16(AL, BH, ACC, 0, 0, 0);

// ---------- GRU + BN partial stats; global_load_lds staging (round-12 proven) ----------
// 4 waves / 64 nodes. Per nt: barrier -> 12 x global_load_lds (48KB, linear,
// conflict-free) -> barrier (vmcnt drained) -> lane-linear b128 + 72 MFMA.
__global__ __launch_bounds__(256) void k_gru(
    const float* __restrict__ aggr, const float* __restrict__ hf,
    const u16* __restrict__ pW,
    const float* __restrict__ c2, const float* __restrict__ bih,
    const float* __restrict__ bhh, const int* __restrict__ degi,
    float* __restrict__ hgru, double* __restrict__ partials) {
  __shared__ uint4 wlds4[12 * 256];   // 48 KB
  u16* wlds = (u16*)wlds4;
  const int t = threadIdx.x;
  const int ln = t & 63, wv = t >> 6;
  const int lr = ln & 15, lg = ln >> 4;
  const int nb = blockIdx.x * 64 + wv * 16;
  const int rowc = min(nb + lr, NN - 1);
  const size_t prow = ((size_t)blockIdx.x * 4 + wv) * 256;

  bf16x8 Aah[4], Aal[4], Ahh[4], Ahl[4];
  #pragma unroll
  for (int kk = 0; kk < 4; ++kk) {
    int c0 = kk * 32 + lg * 8;
    split8(aggr + (size_t)rowc * 128 + c0, Aah[kk], Aal[kk]);
    split8(hf + (size_t)rowc * 128 + c0, Ahh[kk], Ahl[kk]);
  }

  float degs[4];
  int noderow[4];
  #pragma unroll
  for (int r = 0; r < 4; ++r) {
    noderow[r] = min(nb + lg * 4 + r, NN - 1);
    degs[r] = (float)degi[noderow[r]];
  }

  #pragma unroll 1
  for (int nt = 0; nt < 8; ++nt) {
    const int col = nt * 16 + lr;

    // hold loads issued early; consumed only in the epilogue
    float fh[4];
    #pragma unroll
    for (int r = 0; r < 4; ++r)
      fh[r] = hf[(size_t)noderow[r] * 128 + col];

    __syncthreads();   // all waves done reading previous nt's tiles
    #pragma unroll
    for (int j = 0; j < 12; ++j) {
      size_t gidx = (size_t)nt * 3072 + j * 256 + t;   // granule index
      gload16(pW + gidx * 8, wlds + (size_t)(j * 256 + t) * 8);
    }
    __syncthreads();   // compiler drains vmcnt(0) before barrier -> tiles ready

    f32x4 ar = (f32x4){0.f, 0.f, 0.f, 0.f};
    f32x4 az = ar, ai = ar, an = ar;
    #pragma unroll
    for (int kk = 0; kk < 4; ++kk) {
      const bf16x8* wb = (const bf16x8*)wlds + kk * 64 + ln;   // lane-linear
      bf16x8 brh = wb[0 * 256];
      bf16x8 brl = wb[1 * 256];
      bf16x8 crh = wb[2 * 256];
      bf16x8 crl = wb[3 * 256];
      MFMA3(ar, Aah[kk], Aal[kk], brh, brl)
      MFMA3(ar, Ahh[kk], Ahl[kk], crh, crl)
      bf16x8 bzh = wb[4 * 256];
      bf16x8 bzl = wb[5 * 256];
      bf16x8 czh = wb[6 * 256];
      bf16x8 czl = wb[7 * 256];
      MFMA3(az, Aah[kk], Aal[kk], bzh, bzl)
      MFMA3(az, Ahh[kk], Ahl[kk], czh, czl)
      bf16x8 bnh = wb[8 * 256];
      bf16x8 bnl = wb[9 * 256];
      bf16x8 cnh = wb[10 * 256];
      bf16x8 cnl = wb[11 * 256];
      MFMA3(ai, Aah[kk], Aal[kk], bnh, bnl)
      MFMA3(an, Ahh[kk], Ahl[kk], cnh, cnl)
    }

    float c2r = c2[col], c2z = c2[128 + col], c2n = c2[256 + col];
    float br = bih[col] + bhh[col];
    float bz = bih[128 + col] + bhh[128 + col];
    float bin_ = bih[256 + col], bhn = bhh[256 + col];
    double s = 0.0, s2 = 0.0;
    #pragma unroll
    for (int r = 0; r < 4; ++r) {
      int node = nb + lg * 4 + r;
      bool valid = node < NN;
      float d = degs[r];
      float sr = ar[r] + d * c2r + br;
      float sz = az[r] + d * c2z + bz;
      float rg = 1.f / (1.f + __expf(-sr));
      float zg = 1.f / (1.f + __expf(-sz));
      float ngin = ai[r] + d * c2n + bin_ + rg * (an[r] + bhn);
      float e2 = __expf(-2.f * fabsf(ngin));
      float ng = __builtin_copysignf((1.f - e2) / (1.f + e2), ngin);
      float hn = (1.f - zg) * ng + zg * fh[r];
      if (valid) {
        hgru[(size_t)node * 128 + col] = hn;
        s += (double)hn;
        s2 += (double)hn * (double)hn;
      }
    }
    s += __shfl_xor(s, 16);  s += __shfl_xor(s, 32);
    s2 += __shfl_xor(s2, 16); s2 += __shfl_xor(s2, 32);
    if (lg == 0) {
      partials[prow + col] = s;
      partials[prow + 128 + col] = s2;
    }
  }
}

// ---------- BN stats reduction (deterministic, f64) ----------
__global__ void k_bnred_a(const double* __restrict__ partials, double* __restrict__ interm) {
  int b = blockIdx.x;       // 64
  int c = threadIdx.x;      // 256
  double s = 0.0;
  int i0 = b * 98, i1 = min(i0 + 98, NPART);
  for (int i = i0; i < i1; ++i) s += partials[(size_t)i * 256 + c];
  interm[b * 256 + c] = s;
}
__global__ void k_bnred_b(const double* __restrict__ interm, const float* __restrict__ gamma,
                          const float* __restrict__ beta, float* __restrict__ bnsc,
                          float* __restrict__ bnsh) {
  int c = threadIdx.x;      // 128
  double s = 0.0, s2 = 0.0;
  for (int i = 0; i < 64; ++i) {
    s += interm[i * 256 + c];
    s2 += interm[i * 256 + 128 + c];
  }
  double mu = s / (double)NN;
  double var = s2 / (double)NN - mu * mu;
  float sc = (float)((double)gamma[c] / sqrt(var + (double)BN_EPS));
  bnsc[c] = sc;
  bnsh[c] = (float)((double)beta[c] - mu * (double)sc);
}

// ---------- final BN apply + residual (last layer only; in-place elementwise) ----------
__global__ void k_bnapply(const float* __restrict__ hgru, const float* __restrict__ bnsc,
                          const float* __restrict__ bnsh, float* __restrict__ hf) {
  int i = blockIdx.x * 256 + threadIdx.x;  // NN*HH/4 exact
  int c4 = i & 31;
  float4 g = ((const float4*)hgru)[i];
  float4 sc = ((const float4*)bnsc)[c4];
  float4 sh = ((const float4*)bnsh)[c4];
  float4 h = ((const float4*)hf)[i];
  float4 o;
  o.x = g.x * sc.x + sh.x + h.x;
  o.y = g.y * sc.y + sh.y + h.y;
  o.z = g.z * sc.z + sh.z + h.z;
  o.w = g.w * sc.w + sh.w + h.w;
  ((float4*)hf)[i] = o;
}

// ---------- output ----------
__global__ void k_out(const float* __restrict__ hf, const float* __restrict__ wout,
                      const float* __restrict__ bout, float* __restrict__ out) {
  int ln = threadIdx.x & 63;
  int n = blockIdx.x * 4 + (threadIdx.x >> 6);
  float2 w = ((const float2*)wout)[ln];
  float2 v = ((const float2*)(hf + (size_t)n * 128))[ln];
  float s = v.x * w.x + v.y * w.y;
  #pragma unroll
  for (int d = 32; d > 0; d >>= 1) s += __shfl_xor(s, d);
  if (ln == 0) out[n] = s + bout[0];
}

extern "C" void kernel_launch(void* const* d_in, const int* in_sizes, int n_in,
                              void* d_out, int out_size, void* d_ws, size_t ws_size,
                              hipStream_t stream) {
  const float* x = (const float*)d_in[0];
  const int* eraw = (const int*)d_in[1];
  const float* Win = (const float*)d_in[2];
  const float* bin = (const float*)d_in[3];
  const float* mW1 = (const float*)d_in[4];
  const float* mb1 = (const float*)d_in[5];
  const float* mW2 = (const float*)d_in[6];
  const float* mb2 = (const float*)d_in[7];
  const float* Wih = (const float*)d_in[8];
  const float* bih = (const float*)d_in[9];
  const float* Whh = (const float*)d_in[10];
  const float* bhh = (const float*)d_in[11];
  const float* gamma = (const float*)d_in[12];
  const float* beta = (const float*)d_in[13];
  const float* wout = (const float*)d_in[14];
  const float* bout = (const float*)d_in[15];
  float* out = (float*)d_out;

  char* ws = (char*)d_ws;
  size_t off = 0;
  auto carve = [&](size_t b) -> char* {
    char* p = ws + off;
    off = (off + b + 255) & ~(size_t)255;
    return p;
  };
  // Big buffers (4 x 51.2 MB) with lifetime-based aliasing:
  //   Hbuf[l&1]      : h_l (ping-pong)
  //   Hbuf[(l+1)&1]  : aggr_l (reuses dead h_{l-1}; Hbuf[1] free at l=0)
  //   RG[l&1]        : R_l, then hgru_l (R dead after k_aggr)
  //   RG[(l-1)&1]    : hgru_{l-1} read by k_relu1 (dead after)
  float* Hbuf0 = (float*)carve(sizeof(float) * NN * HH);
  float* Hbuf1 = (float*)carve(sizeof(float) * NN * HH);
  float* RG0 = (float*)carve(sizeof(float) * NN * HH);
  float* RG1 = (float*)carve(sizeof(float) * NN * HH);
  int* es = (int*)carve(sizeof(int) * EE);
  int* idxflag = (int*)carve(sizeof(int) * 64);
  int* degi = (int*)carve(sizeof(int) * NN);
  int* curs = (int*)carve(sizeof(int) * NN);
  int* bsum = (int*)carve(sizeof(int) * SCAN_BLK);
  double* partials = (double*)carve(sizeof(double) * NPART * 256);
  double* interm = (double*)carve(sizeof(double) * 64 * 256);
  float* bnsc = (float*)carve(sizeof(float) * 128);
  float* bnsh = (float*)carve(sizeof(float) * 128);
  u16* W1h = (u16*)carve(sizeof(u16) * 4 * HH * HH);
  u16* W1l = (u16*)carve(sizeof(u16) * 4 * HH * HH);
  float* Wff = (float*)carve(sizeof(float) * 4 * 384 * HH);
  u16* pW = (u16*)carve(sizeof(u16) * 4 * 24576 * 8);   // nt-major packed GRU weights
  float* c2 = (float*)carve(sizeof(float) * 4 * 384);
  // total ~228 MB (round-5's 247 MB fit; round-7's 292 MB crashed)

  float* Hbuf[2] = {Hbuf0, Hbuf1};
  float* RG[2] = {RG0, RG1};

  // ---- index dtype probe (no extracted copy; CSR kernels read eraw) ----
  k_idx_probe<<<1, 64, 0, stream>>>(eraw, idxflag);

  // ---- CSR build (dst-sorted edges; curs ends as row-end array) ----
  hipMemsetAsync(degi, 0, sizeof(int) * NN, stream);
  k_hist<<<(EE + 255) / 256, 256, 0, stream>>>(eraw, idxflag, degi);
  k_scan1<<<SCAN_BLK, 256, 0, stream>>>(degi, curs, bsum);
  k_scan2<<<1, 64, 0, stream>>>(bsum);
  k_scan3<<<SCAN_BLK, 256, 0, stream>>>(curs, bsum);
  k_scatter<<<(EE + 255) / 256, 256, 0, stream>>>(eraw, idxflag, curs, es);

  // ---- weight prep ----
  k_split<<<(4 * HH * HH / 4) / 256, 256, 0, stream>>>(mW1, W1h, W1l, 4 * HH * HH / 4);
  k_fuse_wf<<<4 * 384, 128, 0, stream>>>(Wih, mW2, Wff);
  k_packsplit2<<<384, 256, 0, stream>>>(Wff, Whh, pW);
  k_c2<<<6, 256, 0, stream>>>(Wih, mb2, c2);

  // ---- state init: h_0 -> Hbuf[0] ----
  k_inproj2<<<(NN + 63) / 64, 256, 0, stream>>>(x, Win, bin, Hbuf[0]);

  for (int l = 0; l < LL; ++l) {
    const float* h_old = Hbuf[(l == 0) ? 0 : ((l - 1) & 1)];  // h_{l-1}
    float* h_cur = Hbuf[l & 1];                               // h_l
    float* Rbuf = RG[l & 1];                                  // R_l, later hgru_l
    const float* hgru_prev = RG[(l == 0) ? 1 : ((l - 1) & 1)];// hgru_{l-1} (unused at l=0)
    float* aggr = Hbuf[(l + 1) & 1];                          // reuses dead h_{l-1}
    // R = relu(h_l @ W1^T + b1); for l>0 also materializes h_l = BN(hgru_{l-1})+h_{l-1}
    k_relu1<<<(NN + 63) / 64, 256, 0, stream>>>(
        hgru_prev, bnsc, bnsh, h_old, h_cur,
        W1h + (size_t)l * HH * HH, W1l + (size_t)l * HH * HH,
        mb1 + l * HH, Rbuf, l > 0 ? 1 : 0);
    k_aggr<<<(NN + 3) / 4, 256, 0, stream>>>(Rbuf, es, curs, aggr);
    k_gru<<<(NN + 63) / 64, 256, 0, stream>>>(
        aggr, h_cur, pW + (size_t)l * 24576 * 8,
        c2 + l * 384, bih + l * 384, bhh + l * 384, degi, Rbuf /*hgru_l*/, partials);
    k_bnred_a<<<64, 256, 0, stream>>>(partials, interm);
    k_bnred_b<<<1, 128, 0, stream>>>(interm, gamma + l * HH, beta + l * HH, bnsc, bnsh);
  }
  // final h_4 = BN(hgru_3) + h_3 ; hgru_3 in RG[(LL-1)&1], h_3 in Hbuf[(LL-1)&1]
  k_bnapply<<<(NN * HH / 4) / 256, 256, 0, stream>>>(RG[(LL - 1) & 1], bnsc, bnsh,
                                                     Hbuf[(LL - 1) & 1]);
  k_out<<<NN / 4, 256, 0, stream>>>(Hbuf[(LL - 1) & 1], wout, bout, out);
}